// Round 1
// baseline (34703.015 us; speedup 1.0000x reference)
//
#include <hip/hip_runtime.h>
#include <hip/hip_bf16.h>
#include <math.h>

// Problem constants
#define EMB 400
#define HID 300
#define KEY 128
#define VAL 128
#define VOCAB 33
#define T_STEPS 256
#define B 256
#define S 512
#define KT 428        // ctx(128) + h(300)
#define GATES 1200    // 4*HID

__device__ __forceinline__ float sigmoidf_(float x) {
    return 1.f / (1.f + expf(-x));
}

// ---------------- Precompute: E2[v][j] = b_ih[j] + b_hh[j] + sum_e emb[v][e]*W_ih[j][e]
__global__ __launch_bounds__(256) void p1_e2(
    const float* __restrict__ emb, const float* __restrict__ Wih,
    const float* __restrict__ bih, const float* __restrict__ bhh,
    float* __restrict__ E2)
{
    __shared__ float es[EMB];
    const int v = blockIdx.x;
    for (int i = threadIdx.x; i < EMB; i += 256) es[i] = emb[v * EMB + i];
    __syncthreads();
    for (int j = threadIdx.x; j < GATES; j += 256) {
        float s = bih[j] + bhh[j];
        const float* wr = &Wih[(size_t)j * (EMB + VAL)];
        #pragma unroll 4
        for (int e = 0; e < EMB; ++e) s += es[e] * wr[e];
        E2[v * GATES + j] = s;
    }
}

// ---------------- Precompute: phi_wT transpose + broadcast h0/c0 into h/c
__global__ __launch_bounds__(256) void p2_init(
    const float* __restrict__ phi_w, const float* __restrict__ h0,
    const float* __restrict__ c0,
    float* __restrict__ phi_wT, float* __restrict__ h, float* __restrict__ c)
{
    int i = blockIdx.x * 256 + threadIdx.x;
    if (i < KEY * HID) {
        int k = i / HID, ii = i % HID;        // phi_w[k][ii]
        phi_wT[ii * KEY + k] = phi_w[i];
    }
    if (i < B * HID) {
        int ii = i % HID;
        h[i] = h0[ii];
        c[i] = c0[ii];
    }
}

// ---------------- K1: fused gates GEMM + LSTM cell update
// gates[b][g*300+n] = E2[x[b]][g*300+n] + sum_{k<128} ctx[b][k]*W_ih[j][400+k]
//                                       + sum_{k<300} h_in[b][k]*W_hh[j][k]
// then c,h update in epilogue. Tile: 16 b x 16 n, all 4 gates per thread.
#define TB 16
#define TN 16
#define BK 32
__global__ __launch_bounds__(256) void k1_lstm(
    const int* __restrict__ xt,        // B ints for this step
    const float* __restrict__ Wih,     // [1200][528]
    const float* __restrict__ Whh,     // [1200][300]
    const float* __restrict__ E2,      // [33][1200]
    const float* __restrict__ ctx,     // [256][128]
    const float* __restrict__ h_in,    // [256][300]
    float* __restrict__ h_out,         // [256][300]
    float* __restrict__ c)             // [256][300] in-place
{
    __shared__ float As[TB][BK + 1];
    __shared__ float Ws[4][TN][BK + 1];
    const int tid = threadIdx.x;
    const int nl = tid & 15;
    const int bl = tid >> 4;
    const int b0 = blockIdx.x * TB;
    const int n0 = blockIdx.y * TN;
    const int b = b0 + bl;
    const int n = n0 + nl;
    const bool valid = (n < HID);

    const int xb = xt[b];
    float acc[4];
    #pragma unroll
    for (int g = 0; g < 4; ++g)
        acc[g] = valid ? E2[xb * GATES + g * HID + n] : 0.f;

    for (int k0 = 0; k0 < KT; k0 += BK) {
        // A tile: 16 x 32 (ctx for k<128, h for k>=128; 128%32==0 so tiles are pure)
        #pragma unroll
        for (int r = 0; r < 2; ++r) {
            int e = r * 256 + tid;
            int bb = e >> 5, kk = e & 31;
            int k = k0 + kk;
            float vv = 0.f;
            if (k < KT) {
                int gb = b0 + bb;
                vv = (k < VAL) ? ctx[gb * VAL + k] : h_in[gb * HID + (k - VAL)];
            }
            As[bb][kk] = vv;
        }
        // W tile: 4 x 16 x 32
        #pragma unroll
        for (int r = 0; r < 8; ++r) {
            int e = r * 256 + tid;
            int g = e >> 9;
            int rem = e & 511;
            int nn = rem >> 5, kk = rem & 31;
            int k = k0 + kk;
            int jn = n0 + nn;
            float vv = 0.f;
            if (k < KT && jn < HID) {
                int j = g * HID + jn;
                vv = (k < VAL) ? Wih[(size_t)j * (EMB + VAL) + EMB + k]
                               : Whh[(size_t)j * HID + (k - VAL)];
            }
            Ws[g][nn][kk] = vv;
        }
        __syncthreads();
        #pragma unroll
        for (int kk = 0; kk < BK; ++kk) {
            float a = As[bl][kk];
            #pragma unroll
            for (int g = 0; g < 4; ++g) acc[g] += a * Ws[g][nl][kk];
        }
        __syncthreads();
    }

    if (valid) {
        float ig = sigmoidf_(acc[0]);
        float fg = sigmoidf_(acc[1]);
        float gg = tanhf(acc[2]);
        float og = sigmoidf_(acc[3]);
        float cn = fg * c[b * HID + n] + ig * gg;
        c[b * HID + n] = cn;
        h_out[b * HID + n] = og * tanhf(cn);
    }
}

// ---------------- K2: per-b fused logits + attention (q, energy, softmax, ctx)
// block = one batch row b, 512 threads.
__global__ __launch_bounds__(512) void k2_attn(
    const float* __restrict__ keys,     // [512][256][128]
    const float* __restrict__ values,   // [512][256][128]
    const float* __restrict__ phi_wT,   // [300][128]
    const float* __restrict__ phi_b,    // [128]
    const float* __restrict__ projw,    // [33][428]
    const float* __restrict__ projb,    // [33]
    const float* __restrict__ h,        // [256][300]  (new h)
    float* __restrict__ ctx,            // [256][128]  old in / new out
    float* __restrict__ out,            // &logits[t][0][0] or nullptr
    int do_ctx)
{
    __shared__ float hh[HID];
    __shared__ float cx[VAL];
    __shared__ __align__(16) float q[KEY];
    __shared__ float en[S];
    __shared__ float qp[4][KEY];
    __shared__ float lp[VOCAB][8];
    __shared__ float cp[4][VAL];
    __shared__ float redm[8];
    __shared__ float reds[8];

    const int t = threadIdx.x;
    const int b = blockIdx.x;

    if (t < HID) hh[t] = h[b * HID + t];
    if (t < VAL) cx[t] = ctx[b * VAL + t];
    __syncthreads();

    // ---- logits = [h | ctx_old] @ proj_w.T + proj_b  (uses OLD ctx)
    if (out != nullptr) {
        if (t < VOCAB * 8) {
            int v = t >> 3, j = t & 7;
            float s = 0.f;
            for (int k = j; k < KT; k += 8) {
                float a = (k < HID) ? hh[k] : cx[k - HID];
                s += a * projw[v * KT + k];
            }
            lp[v][j] = s;
        }
        __syncthreads();
        if (t < VOCAB) {
            float s = projb[t];
            #pragma unroll
            for (int j = 0; j < 8; ++j) s += lp[t][j];
            out[b * VOCAB + t] = s;
        }
    }

    if (!do_ctx) return;

    // ---- q[k] = phi_b[k] + sum_i hh[i] * phi_wT[i][k]
    {
        int k = t & 127, qtr = t >> 7;           // 4 quarters x 75 i's
        float s = 0.f;
        int i0 = qtr * 75;
        for (int i = i0; i < i0 + 75; ++i) s += hh[i] * phi_wT[i * KEY + k];
        qp[qtr][k] = s;
    }
    __syncthreads();
    if (t < KEY) q[t] = phi_b[t] + qp[0][t] + qp[1][t] + qp[2][t] + qp[3][t];
    __syncthreads();

    // ---- energy[s] = q . keys[s][b][:]   (16 lanes per s, float4 loads)
    {
        const int lane16 = t & 15;
        const int grp = t >> 4;                  // 0..31
        const float4* q4 = reinterpret_cast<const float4*>(q);
        #pragma unroll 2
        for (int it = 0; it < 16; ++it) {
            int s = it * 32 + grp;
            const float4* kp = reinterpret_cast<const float4*>(&keys[((size_t)s * B + b) * KEY]);
            int kb = lane16 * 2;
            float4 k0 = kp[kb], k1 = kp[kb + 1];
            float4 q0 = q4[kb], q1 = q4[kb + 1];
            float e = k0.x * q0.x + k0.y * q0.y + k0.z * q0.z + k0.w * q0.w
                    + k1.x * q1.x + k1.y * q1.y + k1.z * q1.z + k1.w * q1.w;
            e += __shfl_xor(e, 1);
            e += __shfl_xor(e, 2);
            e += __shfl_xor(e, 4);
            e += __shfl_xor(e, 8);
            if (lane16 == 0) en[s] = e;
        }
    }
    __syncthreads();

    // ---- softmax over en[0..511]
    {
        float m = en[t];
        #pragma unroll
        for (int off = 32; off; off >>= 1) m = fmaxf(m, __shfl_xor(m, off));
        int w = t >> 6;
        if ((t & 63) == 0) redm[w] = m;
        __syncthreads();
        m = redm[0];
        #pragma unroll
        for (int i = 1; i < 8; ++i) m = fmaxf(m, redm[i]);
        float e = expf(en[t] - m);
        float ss = e;
        #pragma unroll
        for (int off = 32; off; off >>= 1) ss += __shfl_xor(ss, off);
        if ((t & 63) == 0) reds[w] = ss;
        __syncthreads();
        float Ssum = reds[0];
        #pragma unroll
        for (int i = 1; i < 8; ++i) Ssum += reds[i];
        en[t] = e * (1.f / Ssum);
    }
    __syncthreads();

    // ---- ctx[v] = sum_s att[s] * values[s][b][v]
    {
        int v = t & 127, qtr = t >> 7;
        float a = 0.f;
        int s0 = qtr * 128;
        #pragma unroll 4
        for (int s = s0; s < s0 + 128; ++s)
            a += en[s] * values[((size_t)s * B + b) * VAL + v];
        cp[qtr][v] = a;
    }
    __syncthreads();
    if (t < VAL) ctx[b * VAL + t] = cp[0][t] + cp[1][t] + cp[2][t] + cp[3][t];
}

extern "C" void kernel_launch(void* const* d_in, const int* in_sizes, int n_in,
                              void* d_out, int out_size, void* d_ws, size_t ws_size,
                              hipStream_t stream)
{
    const int*   input     = (const int*)  d_in[0];   // [T][B]
    const float* keys      = (const float*)d_in[1];   // [S][B][KEY]
    const float* values    = (const float*)d_in[2];   // [S][B][VAL]
    const float* embedding = (const float*)d_in[3];   // [VOCAB][EMB]
    const float* phi_w     = (const float*)d_in[4];   // [KEY][HID]
    const float* phi_b     = (const float*)d_in[5];   // [KEY]
    const float* h0        = (const float*)d_in[6];   // [1][HID]
    const float* c0        = (const float*)d_in[7];   // [1][HID]
    const float* W_ih      = (const float*)d_in[8];   // [1200][528]
    const float* b_ih      = (const float*)d_in[9];
    const float* W_hh      = (const float*)d_in[10];  // [1200][300]
    const float* b_hh      = (const float*)d_in[11];
    const float* proj_w    = (const float*)d_in[12];  // [33][428]
    const float* proj_b    = (const float*)d_in[13];
    float* out = (float*)d_out;

    float* ws = (float*)d_ws;
    float* hA     = ws;                    // 256*300
    float* hB     = hA + B * HID;          // 256*300
    float* c      = hB + B * HID;          // 256*300
    float* ctx    = c + B * HID;           // 256*128
    float* E2     = ctx + B * VAL;         // 33*1200
    float* phi_wT = E2 + VOCAB * GATES;    // 300*128

    p1_e2<<<VOCAB, 256, 0, stream>>>(embedding, W_ih, b_ih, b_hh, E2);
    p2_init<<<(B * HID + 255) / 256, 256, 0, stream>>>(phi_w, h0, c0, phi_wT, hA, c);

    // initial ctx = attend(h_init); no logits
    k2_attn<<<B, 512, 0, stream>>>(keys, values, phi_wT, phi_b, proj_w, proj_b,
                                   hA, ctx, nullptr, 1);

    float* hin = hA;
    float* hout = hB;
    for (int t = 0; t < T_STEPS; ++t) {
        k1_lstm<<<dim3(B / TB, (HID + TN - 1) / TN), 256, 0, stream>>>(
            input + t * B, W_ih, W_hh, E2, ctx, hin, hout, c);
        k2_attn<<<B, 512, 0, stream>>>(keys, values, phi_wT, phi_b, proj_w, proj_b,
                                       hout, ctx, out + (size_t)t * B * VOCAB,
                                       (t < T_STEPS - 1) ? 1 : 0);
        float* tmp = hin; hin = hout; hout = tmp;
    }
}